// Round 2
// baseline (297.980 us; speedup 1.0000x reference)
//
#include <hip/hip_runtime.h>

typedef unsigned int u32;
typedef unsigned short u16;
typedef __attribute__((ext_vector_type(8))) short bf16x8;  // 8 bf16 = 4 VGPRs
typedef __attribute__((ext_vector_type(4))) float f32x4;

#define KN 8192
#define DD 256
#define HW 1024
#define NP 32768
#define SPLITS 2
#define KSPLIT 4096
#define BROW 256                 // rows (z points) per block, A resident in LDS
#define BCOL 128                 // cols (codebook entries) per streamed B tile
#define NTILES (KSPLIT / BCOL)   // 32

__device__ __forceinline__ u16 rne_bf16(float x) {
    u32 u = __float_as_uint(x);
    return (u16)((u + 0x7FFF + ((u >> 16) & 1)) >> 16);
}

__device__ __forceinline__ void glds16(const void* g, void* ldsbase) {
    __builtin_amdgcn_global_load_lds((const __attribute__((address_space(1))) u32*)g,
                                     (__attribute__((address_space(3))) u32*)ldsbase, 16, 0, 0);
}

// ---------------- merged prep: enorm | eT/eTf transpose | A build (unchanged, proven) ----------------
__global__ void prep_kernel(const float* __restrict__ e, const float* __restrict__ z,
                            u16* __restrict__ eT, float* __restrict__ eTf,
                            float* __restrict__ e2f, u16* __restrict__ A) {
    const int t = threadIdx.x;
    const int bid = blockIdx.x;
    if (bid < 32) {
        int k = bid * 256 + t;
        float acc = 0.f;
#pragma unroll 8
        for (int d = 0; d < DD; ++d) {
            float v = e[(size_t)d * KN + k];
            acc = fmaf(v, v, acc);
        }
        e2f[k] = acc;
    } else if (bid < 544) {
        __shared__ float tt[64][65];
        const int b2 = bid - 32;
        const int kt = b2 & 127;     // 0..127
        const int dt = b2 >> 7;      // 0..3
        const float* ep = e + (size_t)(dt * 64) * KN + kt * 64;
        {
            int k = t & 63, d0 = t >> 6;
#pragma unroll
            for (int j = 0; j < 16; ++j) tt[d0 + j * 4][k] = ep[(size_t)(d0 + j * 4) * KN + k];
        }
        __syncthreads();
        int k = t >> 2, c0 = (t & 3) * 16;
        u16 hi[16];
        float fv[16];
#pragma unroll
        for (int j = 0; j < 16; ++j) {
            float v = tt[c0 + j][k];
            fv[j] = v;
            hi[j] = rne_bf16(v);
        }
        u16* rowp = eT + (size_t)(kt * 64 + k) * 256 + dt * 64 + c0;
        *(uint4*)(rowp) = *(uint4*)(hi);
        *(uint4*)(rowp + 8) = *(uint4*)(hi + 8);
        float* rowpf = eTf + (size_t)(kt * 64 + k) * 256 + dt * 64 + c0;
#pragma unroll
        for (int j = 0; j < 4; ++j) *(float4*)(rowpf + j * 4) = *(float4*)(fv + j * 4);
    } else {
        __shared__ float tt[64][65];
        const int b3 = bid - 544;
        const int pt = b3 & 15;          // 0..15
        const int dt = (b3 >> 4) & 3;    // 0..3
        const int b  = b3 >> 6;          // 0..31
        const float* zp = z + (size_t)b * (DD * HW) + (size_t)(dt * 64) * HW + pt * 64;
        {
            int p = t & 63, d0 = t >> 6;
#pragma unroll
            for (int j = 0; j < 16; ++j) tt[d0 + j * 4][p] = zp[(size_t)(d0 + j * 4) * HW + p];
        }
        __syncthreads();
        int p = t >> 2, c0 = (t & 3) * 16;
        int n = b * HW + pt * 64 + p;
        u16 hi[16];
#pragma unroll
        for (int j = 0; j < 16; ++j) hi[j] = rne_bf16(tt[c0 + j][p]);
        u16* rowp = A + (size_t)n * 256 + dt * 64 + c0;
        *(uint4*)(rowp) = *(uint4*)(hi);
        *(uint4*)(rowp + 8) = *(uint4*)(hi + 8);
    }
}

// ---------------- main: 512-thread, A-resident (128 KB), B kit-dbuf 2-phase MFMA argmin ----------------
// R2 design notes (post-mortem driven):
//  - R1 failed on (a) register spill (acc[4][8]=128 + bounds(512,2) cap -> 21 MB scratch writes)
//    and (b) a broken 4-slot/64B-row swizzle (1.26e7 bank conflicts).
//  - This round: wave tile 64x64 (mi=4, ni=4 -> acc[4][4]=64 regs, goes to AGPRs; non-acc VGPR ~100),
//    and the R7-PROVEN LDS layout: 128-B rows, 8 slots of 16 B, phys slot = (kc*4+g) ^ (row&7),
//    staged via pre-swizzled global source (swz = (l&7)^((l>>3)&7)) into linear glds16 dest.
//  - A resident: Ast[4 kits][256 rows][64 u16] = 128 KB, staged once in prologue.
//    B double-buffered: Bd[2][128 rows][64 u16] = 32 KB. Total 160 KB (1 block/CU, 8 waves = 2/SIMD).
//  - T3-minimum 2-phase per kit: issue next-B stage (2 glds16/wave) -> compute (2 kc x (8 ds_read_b128
//    + 16 MFMA, setprio around MFMA)) -> single __syncthreads (vmcnt(0) drain lands after ~1250 cyc
//    of MFMA, so the L2 stage latency is hidden). 1 barrier/kit vs R7's 2.
//  - ds_reads/wave per 32 MFMA: 16 (vs R7's 20) -> LDS pipe ~= MFMA pipe; stage traffic is L2-hot
//    (eT half = 2 MB/XCD, resident).
//  - Top-3 per row over two wn col-halves + LDS merge: byte-identical keys semantics to R7
//    (merge path correctness-proven in R1: absmax 0.0).

#define STAGE_B(n0_, kit_, buf_)                                                  \
    do {                                                                          \
        const u16* bp_ = bsrcw + (size_t)(n0_) * 256 + (kit_) * 64;               \
        glds16(bp_,           &Bd[buf_][(w * 16) * 64]);                          \
        glds16(bp_ + 8 * 256, &Bd[buf_][(w * 16 + 8) * 64]);                      \
    } while (0)

#define COMPUTE_KIT(kit_, cur_, first_)                                           \
    do {                                                                          \
        _Pragma("unroll")                                                         \
        for (int kc = 0; kc < 2; ++kc) {                                          \
            const int sl_ = ((kc * 4 + g) ^ (fr & 7)) * 8;                        \
            const int ao_ = (wm * 64 + fr) * 64 + sl_;                            \
            const int bo_ = (wn * 64 + fr) * 64 + sl_;                            \
            bf16x8 af[4], bfr[4];                                                 \
            _Pragma("unroll")                                                     \
            for (int mi = 0; mi < 4; ++mi)                                        \
                af[mi] = *(const bf16x8*)&Ast[kit_][ao_ + mi * 1024];             \
            _Pragma("unroll")                                                     \
            for (int ni = 0; ni < 4; ++ni)                                        \
                bfr[ni] = *(const bf16x8*)&Bd[cur_][bo_ + ni * 1024];             \
            __builtin_amdgcn_s_setprio(1);                                        \
            _Pragma("unroll")                                                     \
            for (int mi = 0; mi < 4; ++mi)                                        \
                _Pragma("unroll")                                                 \
                for (int ni = 0; ni < 4; ++ni)                                    \
                    acc[mi][ni] = __builtin_amdgcn_mfma_f32_16x16x32_bf16(        \
                        af[mi], bfr[ni],                                          \
                        ((first_) && kc == 0) ? zacc : acc[mi][ni], 0, 0, 0);     \
            __builtin_amdgcn_s_setprio(0);                                        \
        }                                                                         \
    } while (0)

__launch_bounds__(512, 2)
__global__ void argmin_mfma_kernel(const u16* __restrict__ A,   // [32768][256]
                                   const u16* __restrict__ eT,  // [8192][256]
                                   const float* __restrict__ e2f,
                                   int* __restrict__ keys) {    // [3][2][NP]
    __shared__ __align__(16) u16 Ast[4][BROW * 64];  // 128 KB: [kit][row 256][slot 8][8]
    __shared__ __align__(16) u16 Bd[2][BCOL * 64];   // 2x16 KB: [row 128][slot 8][8]

    const int t = threadIdx.x;
    const int w = t >> 6;        // wave 0..7
    const int l = t & 63;
    const int wm = w & 3;        // M-group 0..3 (64 rows each)
    const int wn = w >> 2;       // N-group 0..1 (64 cols each)
    const int fr = l & 15;
    const int g  = l >> 4;

    const int split = blockIdx.x & 1;
    const int pxt   = blockIdx.x >> 1;   // 0..127
    const int px0 = pxt * BROW;
    const int kb0 = split * KSPLIT;

    // staging lane constants: R7-proven pre-swizzled global source, linear LDS dest.
    // lane l -> LDS row = base + (l>>3), phys slot = l&7; source K-chunk = (l&7)^((l>>3)&7)
    // so phys slot s of row r holds logical chunk s ^ (r&7).
    const int srow = l >> 3;                  // 0..7
    const int ssw  = ((l & 7) ^ srow) * 8;
    const u16* asrc  = A  + (size_t)(px0 + w * 32 + srow) * 256 + ssw;
    const u16* bsrcw = eT + (size_t)(w * 16 + srow) * 256 + ssw;

    const f32x4 zacc = (f32x4){0.f, 0.f, 0.f, 0.f};
    f32x4 acc[4][4];
    int b1[16], b2[16];
#pragma unroll
    for (int i = 0; i < 16; ++i) { b1[i] = 0x7FFFFFFF; b2[i] = 0x7FFFFFFF; }

    // ---- prologue: B(nt0,kit0) + all of A (A is reused by all 32 nt; 16 glds16/wave) ----
    STAGE_B(kb0, 0, 0);
#pragma unroll
    for (int kit = 0; kit < 4; ++kit)
#pragma unroll
        for (int i = 0; i < 4; ++i)
            glds16(asrc + kit * 64 + (size_t)(i * 8) * 256,
                   &Ast[kit][(w * 32 + i * 8) * 64]);
    __syncthreads();

    // ---- main loop: per kit, stage-next / compute-current / single-drain barrier ----
    for (int nt = 0; nt < NTILES; ++nt) {
        const int n0 = kb0 + nt * BCOL;
#pragma unroll
        for (int kit = 0; kit < 4; ++kit) {
            const int cur = kit & 1;                         // nt*4 is even -> parity by kit only
            if (kit < 3)               STAGE_B(n0, kit + 1, cur ^ 1);
            else if (nt < NTILES - 1)  STAGE_B(n0 + BCOL, 0, cur ^ 1);
            COMPUTE_KIT(kit, cur, kit == 0);
            __syncthreads();
        }

        // epilogue: fold this nt's distances into per-row top-2 running keys (no LDS)
        float e2c[4];
        int   kc4[4];
#pragma unroll
        for (int ni = 0; ni < 4; ++ni) {
            kc4[ni] = n0 + wn * 64 + ni * 16 + fr;
            e2c[ni] = e2f[kc4[ni]] * 256.f;
        }
#pragma unroll
        for (int mi = 0; mi < 4; ++mi)
#pragma unroll
            for (int r = 0; r < 4; ++r) {
                int ky[4];
#pragma unroll
                for (int ni = 0; ni < 4; ++ni) {
                    float d = fmaf(acc[mi][ni][r], -512.f, e2c[ni]);
                    ky[ni] = (int)d * 8192 + kc4[ni];
                }
                int kmin = min(min(ky[0], ky[1]), min(ky[2], ky[3]));
                int s = mi * 4 + r;
                int v1 = min(b1[s], kmin);
                int x  = max(b1[s], kmin);
                b2[s] = min(b2[s], x);
                b1[s] = v1;
            }
    }

    // ---- per-wave 16-lane top-3 tree, then cross-wn merge via LDS (R1-proven path) ----
    int* mrg = (int*)&Bd[0][0];   // 2*256*3 ints = 6 KB, Bd is dead now
#pragma unroll
    for (int s = 0; s < 16; ++s) {
        int c1 = b1[s], c2 = b2[s], c3 = 0x7FFFFFFF;
#pragma unroll
        for (int m = 1; m < 16; m <<= 1) {
            int a1 = __shfl_xor(c1, m, 64);
            int a2 = __shfl_xor(c2, m, 64);
            int a3 = __shfl_xor(c3, m, 64);
            int m1 = min(c1, a1);
            int xx = max(c1, a1);
            int mn2 = min(c2, a2);
            int m2 = min(xx, mn2);
            int m3 = min(min(max(c2, a2), max(xx, mn2)), min(c3, a3));
            c1 = m1; c2 = m2; c3 = m3;
        }
        if (fr == 0) {
            int row = wm * 64 + (s >> 2) * 16 + g * 4 + (s & 3);
            int o = (wn * 256 + row) * 3;
            mrg[o] = c1; mrg[o + 1] = c2; mrg[o + 2] = c3;
        }
    }
    __syncthreads();
    if (t < 256) {
        int a1 = mrg[t * 3], a2 = mrg[t * 3 + 1], a3 = mrg[t * 3 + 2];
        int u1 = mrg[(256 + t) * 3], u2 = mrg[(256 + t) * 3 + 1], u3 = mrg[(256 + t) * 3 + 2];
        int x1 = min(a1, u1), y1 = max(a1, u1);
        int n2 = min(a2, u2), M2 = max(a2, u2);
        int c1 = x1;
        int c2 = min(y1, n2);
        int c3 = min(max(y1, n2), min(M2, min(a3, u3)));
        int row = px0 + t;
        keys[split * NP + row]       = c1;
        keys[(2 + split) * NP + row] = c2;
        keys[(4 + split) * NP + row] = c3;
    }
}

// -------- finalize (fast-ws): dots + select + gather + out + loss, one pass (unchanged) --------
__global__ void finalize_kernel(const int* __restrict__ keys,
                                const float* __restrict__ z,
                                const float* __restrict__ eTf,
                                const float* __restrict__ e2f,
                                float* __restrict__ out,
                                float* __restrict__ loss) {
    __shared__ float smem[DD * 65];   // phase 1: zt[d*65+p]; phase 2: qt[p*257+d]
    __shared__ int   kc[384];
    __shared__ float dval[384];
    __shared__ int   kidx[64];
    const int t = threadIdx.x;
    const int n0 = blockIdx.x * 64;
    const float* zp = z + (size_t)(n0 >> 10) * (DD * HW) + (n0 & (HW - 1));

    for (int i = t; i < DD * 64; i += 256) {
        int d = i >> 6, p = i & 63;
        smem[d * 65 + p] = zp[(size_t)d * HW + p];   // coalesced
    }
    for (int i = t; i < 384; i += 256)
        kc[i] = keys[(i % 6) * NP + n0 + i / 6] & 8191;
    __syncthreads();

    const int l = t & 63, w = t >> 6;
    const int j = l & 15;   // lane within 16-lane dot group
    const int s = l >> 4;   // dot-group id within wave
#pragma unroll 2
    for (int it = 0; it < 24; ++it) {
        int dot = it * 16 + w * 4 + s;      // 0..383
        int p = dot / 6;
        int k = kc[dot];
        const float* er = eTf + (size_t)k * 256;
        float a = 0.f;
#pragma unroll
        for (int cc = 0; cc < 16; ++cc)
            a = fmaf(smem[(cc * 16 + j) * 65 + p], er[cc * 16 + j], a);
        a += __shfl_xor(a, 1, 64);
        a += __shfl_xor(a, 2, 64);
        a += __shfl_xor(a, 4, 64);
        a += __shfl_xor(a, 8, 64);
        if (j == 0) dval[dot] = fmaf(-2.f, a, e2f[k]);
    }
    __syncthreads();
    if (t < 64) {
        float bv = dval[t * 6];
        int   bk = kc[t * 6];
#pragma unroll
        for (int c = 1; c < 6; ++c) {
            float dv = dval[t * 6 + c];
            int   kk = kc[t * 6 + c];
            if (dv < bv || (dv == bv && kk < bk)) { bv = dv; bk = kk; }
        }
        kidx[t] = bk;
    }
    __syncthreads();

    // phase 2: bounce the 64 winning eTf rows through smem (zt is dead)
    float* qt = smem;                 // [p][d] pad 257 (257%32==1: conflict-free)
    for (int m = 0; m < 64; ++m)      // row m: 256 threads read the 1 KB row
        qt[m * 257 + t] = eTf[(size_t)kidx[m] * 256 + t];
    __syncthreads();

    const int p = t & 63, q = t >> 6;
    const size_t base = (size_t)(n0 >> 10) * (DD * HW) + (n0 & (HW - 1)) + p;
    float acc = 0.f;
#pragma unroll 8
    for (int i = 0; i < 64; ++i) {
        int d = q * 64 + i;
        float ev = qt[p * 257 + d];
        float zv = z[base + (size_t)d * HW];   // coalesced, L2-hot re-read
        out[base + (size_t)d * HW] = zv + (ev - zv);
        float df = ev - zv;
        acc = fmaf(df, df, acc);
    }
#pragma unroll
    for (int off = 32; off > 0; off >>= 1) acc += __shfl_down(acc, off, 64);
    __shared__ float part[4];
    if ((t & 63) == 0) part[t >> 6] = acc;
    __syncthreads();
    if (t == 0) {
        float s2 = (part[0] + part[1] + part[2] + part[3]) * (1.25f / 8388608.f);
        atomicAdd(loss, s2);
    }
}

// -------- slow-ws path: R7-proven separate combine + gather (unchanged) --------
__global__ void combine_kernel(const int* __restrict__ keys,
                               const float* __restrict__ z,
                               const float* __restrict__ eTf,
                               const float* __restrict__ e2f,
                               int* __restrict__ idx) {
    __shared__ float zt[DD * 65];
    __shared__ int   kc[384];
    __shared__ float dval[384];
    const int t = threadIdx.x;
    const int n0 = blockIdx.x * 64;
    const float* zp = z + (size_t)(n0 >> 10) * (DD * HW) + (n0 & (HW - 1));
    for (int i = t; i < DD * 64; i += 256) {
        int d = i >> 6, p = i & 63;
        zt[d * 65 + p] = zp[(size_t)d * HW + p];
    }
    for (int i = t; i < 384; i += 256)
        kc[i] = keys[(i % 6) * NP + n0 + i / 6] & 8191;
    __syncthreads();

    const int l = t & 63, w = t >> 6;
    const int j = l & 15;
    const int s = l >> 4;
#pragma unroll 2
    for (int it = 0; it < 24; ++it) {
        int dot = it * 16 + w * 4 + s;
        int p = dot / 6;
        int k = kc[dot];
        const float* er = eTf + (size_t)k * 256;
        float a = 0.f;
#pragma unroll
        for (int cc = 0; cc < 16; ++cc)
            a = fmaf(zt[(cc * 16 + j) * 65 + p], er[cc * 16 + j], a);
        a += __shfl_xor(a, 1, 64);
        a += __shfl_xor(a, 2, 64);
        a += __shfl_xor(a, 4, 64);
        a += __shfl_xor(a, 8, 64);
        if (j == 0) dval[dot] = fmaf(-2.f, a, e2f[k]);
    }
    __syncthreads();
    if (t < 64) {
        float bv = dval[t * 6];
        int   bk = kc[t * 6];
#pragma unroll
        for (int c = 1; c < 6; ++c) {
            float dv = dval[t * 6 + c];
            int   kk = kc[t * 6 + c];
            if (dv < bv || (dv == bv && kk < bk)) { bv = dv; bk = kk; }
        }
        idx[n0 + t] = bk;
    }
}

__global__ void gather_slow_kernel(const float* __restrict__ z,
                                   const float* __restrict__ e,
                                   const int* __restrict__ idx,
                                   float* __restrict__ out,
                                   float* __restrict__ loss) {
    const int t = threadIdx.x;
    const int n0 = blockIdx.x * 64;
    __shared__ int kidx[64];
    if (t < 64) kidx[t] = idx[n0 + t];
    __syncthreads();

    const int p = t & 63;
    const int d0 = t >> 6;
    const size_t base = (size_t)(n0 >> 10) * (DD * HW) + (n0 & (HW - 1)) + p;
    const int kk = kidx[p];

    float acc = 0.f;
    for (int d = d0; d < DD; d += 4) {
        float ev = e[(size_t)d * KN + kk];
        float zv = z[base + (size_t)d * HW];
        out[base + (size_t)d * HW] = zv + (ev - zv);
        float df = ev - zv;
        acc = fmaf(df, df, acc);
    }
#pragma unroll
    for (int off = 32; off > 0; off >>= 1) acc += __shfl_down(acc, off, 64);
    __shared__ float part[4];
    if ((t & 63) == 0) part[t >> 6] = acc;
    __syncthreads();
    if (t == 0) {
        float s = (part[0] + part[1] + part[2] + part[3]) * (1.25f / 8388608.f);
        atomicAdd(loss, s);
    }
}

extern "C" void kernel_launch(void* const* d_in, const int* in_sizes, int n_in,
                              void* d_out, int out_size, void* d_ws, size_t ws_size,
                              hipStream_t stream) {
    const float* z = (const float*)d_in[0];   // [32,256,32,32] fp32
    const float* e = (const float*)d_in[1];   // [256,8192] fp32
    float* out = (float*)d_out;
    float* loss = out + (size_t)NP * DD;      // element 8388608

    char* ob = (char*)d_out;
    char* ws = (char*)d_ws;
    u16* Acat = (u16*)ob;                            // [0, 16Mi) — consumed by argmin
    u16* eT   = (u16*)(ob + ((size_t)16 << 20));     // [16Mi, 20Mi) — consumed by argmin

    float* e2f = (float*)ws;                         // 32 KB (proven-safe region)
    int*   idx = (int*)(ws + (32 << 10));            // 128 KB
    int*   keys;
    float* eTf;
    const bool fastws = ws_size >= ((size_t)10 << 20);
    if (fastws) {
        keys = (int*)(ws + (160 << 10));             // 768 KB @ 160K
        eTf  = (float*)(ws + ((size_t)1 << 20));     // 8 MB @ 1M
    } else {
        keys = (int*)(ob + ((size_t)20 << 20));      // d_out scratch (R6-proven)
        eTf  = (float*)(ob + ((size_t)23 << 20));
    }

    prep_kernel<<<2592, 256, 0, stream>>>(e, z, eT, eTf, e2f, Acat);
    argmin_mfma_kernel<<<SPLITS * (NP / BROW), 512, 0, stream>>>(Acat, eT, e2f, keys);
    hipMemsetAsync(loss, 0, sizeof(float), stream);
    if (fastws) {
        finalize_kernel<<<NP / 64, 256, 0, stream>>>(keys, z, eTf, e2f, out, loss);
    } else {
        combine_kernel<<<NP / 64, 256, 0, stream>>>(keys, z, eTf, e2f, idx);
        gather_slow_kernel<<<NP / 64, 256, 0, stream>>>(z, e, idx, out, loss);
    }
}

// Round 3
// 296.416 us; speedup vs baseline: 1.0053x; 1.0053x over previous
//
#include <hip/hip_runtime.h>

typedef unsigned int u32;
typedef unsigned short u16;
typedef __attribute__((ext_vector_type(8))) short bf16x8;  // 8 bf16 = 4 VGPRs
typedef __attribute__((ext_vector_type(4))) float f32x4;

#define KN 8192
#define DD 256
#define HW 1024
#define NP 32768
#define SPLITS 2
#define KSPLIT 4096
#define BROW 256                 // rows (z points) per block, A resident in LDS
#define BCOL 128                 // cols (codebook entries) per streamed B tile
#define NTILES (KSPLIT / BCOL)   // 32

__device__ __forceinline__ u16 rne_bf16(float x) {
    u32 u = __float_as_uint(x);
    return (u16)((u + 0x7FFF + ((u >> 16) & 1)) >> 16);
}

__device__ __forceinline__ void glds16(const void* g, void* ldsbase) {
    __builtin_amdgcn_global_load_lds((const __attribute__((address_space(1))) u32*)g,
                                     (__attribute__((address_space(3))) u32*)ldsbase, 16, 0, 0);
}

// ---------------- merged prep: enorm | eT/eTf transpose | A build (unchanged, proven) ----------------
__global__ void prep_kernel(const float* __restrict__ e, const float* __restrict__ z,
                            u16* __restrict__ eT, float* __restrict__ eTf,
                            float* __restrict__ e2f, u16* __restrict__ A) {
    const int t = threadIdx.x;
    const int bid = blockIdx.x;
    if (bid < 32) {
        int k = bid * 256 + t;
        float acc = 0.f;
#pragma unroll 8
        for (int d = 0; d < DD; ++d) {
            float v = e[(size_t)d * KN + k];
            acc = fmaf(v, v, acc);
        }
        e2f[k] = acc;
    } else if (bid < 544) {
        __shared__ float tt[64][65];
        const int b2 = bid - 32;
        const int kt = b2 & 127;     // 0..127
        const int dt = b2 >> 7;      // 0..3
        const float* ep = e + (size_t)(dt * 64) * KN + kt * 64;
        {
            int k = t & 63, d0 = t >> 6;
#pragma unroll
            for (int j = 0; j < 16; ++j) tt[d0 + j * 4][k] = ep[(size_t)(d0 + j * 4) * KN + k];
        }
        __syncthreads();
        int k = t >> 2, c0 = (t & 3) * 16;
        u16 hi[16];
        float fv[16];
#pragma unroll
        for (int j = 0; j < 16; ++j) {
            float v = tt[c0 + j][k];
            fv[j] = v;
            hi[j] = rne_bf16(v);
        }
        u16* rowp = eT + (size_t)(kt * 64 + k) * 256 + dt * 64 + c0;
        *(uint4*)(rowp) = *(uint4*)(hi);
        *(uint4*)(rowp + 8) = *(uint4*)(hi + 8);
        float* rowpf = eTf + (size_t)(kt * 64 + k) * 256 + dt * 64 + c0;
#pragma unroll
        for (int j = 0; j < 4; ++j) *(float4*)(rowpf + j * 4) = *(float4*)(fv + j * 4);
    } else {
        __shared__ float tt[64][65];
        const int b3 = bid - 544;
        const int pt = b3 & 15;          // 0..15
        const int dt = (b3 >> 4) & 3;    // 0..3
        const int b  = b3 >> 6;          // 0..31
        const float* zp = z + (size_t)b * (DD * HW) + (size_t)(dt * 64) * HW + pt * 64;
        {
            int p = t & 63, d0 = t >> 6;
#pragma unroll
            for (int j = 0; j < 16; ++j) tt[d0 + j * 4][p] = zp[(size_t)(d0 + j * 4) * HW + p];
        }
        __syncthreads();
        int p = t >> 2, c0 = (t & 3) * 16;
        int n = b * HW + pt * 64 + p;
        u16 hi[16];
#pragma unroll
        for (int j = 0; j < 16; ++j) hi[j] = rne_bf16(tt[c0 + j][p]);
        u16* rowp = A + (size_t)n * 256 + dt * 64 + c0;
        *(uint4*)(rowp) = *(uint4*)(hi);
        *(uint4*)(rowp + 8) = *(uint4*)(hi + 8);
    }
}

// ---------------- main: 512-thread, A-resident (128 KB), counted-vmcnt pipelined MFMA argmin ----------------
// R3 (post-mortem R2): geometry identical to R2 (proven absmax 0.0, 0 bank conflicts, 92 VGPR).
// ONLY the sync structure changes: __syncthreads (vmcnt(0) drain each kit -> fully serialized
// stage/read/MFMA, 3370 cyc/kit measured) is replaced by the T3/T4 counted-vmcnt scheme:
//   per kit: STAGE(kit+1) ; s_waitcnt vmcnt(2)  <- waits PREVIOUS stage only, keeps the
//            just-issued one in flight across the barrier ; s_barrier ; sched_barrier(0) ;
//            ds_read+MFMA (setprio) ; s_barrier ; sched_barrier(0)
// WAR ledger (2 buffers, 2 raw barriers/kit):
//   - buf written at kit i (stage for i+1) was last read at kit i-1 compute; separated by
//     kit i-1's barrier #2.  OK
//   - reads of buf[i&1] at kit i: each wave certifies its OWN 2 stage loads via vmcnt(2)
//     before barrier #1; all 8 waves do so -> whole 16 KB buffer certified at the barrier. OK
//   - vmcnt FIFO: at kit0 of nt, outstanding = [S(nt,0) x2 (issued at prev kit3), S(nt,1) x2
//     (just issued)] -> vmcnt(2) retires S(nt,0). A-prologue (16 loads) retires under the same
//     wait at nt=0. e2f epilogue loads are consumed by their VALU fold before the next wait.
//   - last global kit stages nothing -> vmcnt(0).
// sched_barrier(0) after each raw barrier pins ds_read / glds16 from being hoisted across it.

#define STAGE_B(n0_, kit_, buf_)                                                  \
    do {                                                                          \
        const u16* bp_ = bsrcw + (size_t)(n0_) * 256 + (kit_) * 64;               \
        glds16(bp_,           &Bd[buf_][(w * 16) * 64]);                          \
        glds16(bp_ + 8 * 256, &Bd[buf_][(w * 16 + 8) * 64]);                      \
    } while (0)

#define COMPUTE_KIT(kit_, cur_, first_)                                           \
    do {                                                                          \
        _Pragma("unroll")                                                         \
        for (int kc = 0; kc < 2; ++kc) {                                          \
            const int sl_ = ((kc * 4 + g) ^ (fr & 7)) * 8;                        \
            const int ao_ = (wm * 64 + fr) * 64 + sl_;                            \
            const int bo_ = (wn * 64 + fr) * 64 + sl_;                            \
            bf16x8 af[4], bfr[4];                                                 \
            _Pragma("unroll")                                                     \
            for (int mi = 0; mi < 4; ++mi)                                        \
                af[mi] = *(const bf16x8*)&Ast[kit_][ao_ + mi * 1024];             \
            _Pragma("unroll")                                                     \
            for (int ni = 0; ni < 4; ++ni)                                        \
                bfr[ni] = *(const bf16x8*)&Bd[cur_][bo_ + ni * 1024];             \
            __builtin_amdgcn_s_setprio(1);                                        \
            _Pragma("unroll")                                                     \
            for (int mi = 0; mi < 4; ++mi)                                        \
                _Pragma("unroll")                                                 \
                for (int ni = 0; ni < 4; ++ni)                                    \
                    acc[mi][ni] = __builtin_amdgcn_mfma_f32_16x16x32_bf16(        \
                        af[mi], bfr[ni],                                          \
                        ((first_) && kc == 0) ? zacc : acc[mi][ni], 0, 0, 0);     \
            __builtin_amdgcn_s_setprio(0);                                        \
        }                                                                         \
    } while (0)

__launch_bounds__(512, 2)
__global__ void argmin_mfma_kernel(const u16* __restrict__ A,   // [32768][256]
                                   const u16* __restrict__ eT,  // [8192][256]
                                   const float* __restrict__ e2f,
                                   int* __restrict__ keys) {    // [3][2][NP]
    __shared__ __align__(16) u16 Ast[4][BROW * 64];  // 128 KB: [kit][row 256][slot 8][8]
    __shared__ __align__(16) u16 Bd[2][BCOL * 64];   // 2x16 KB: [row 128][slot 8][8]

    const int t = threadIdx.x;
    const int w = t >> 6;        // wave 0..7
    const int l = t & 63;
    const int wm = w & 3;        // M-group 0..3 (64 rows each)
    const int wn = w >> 2;       // N-group 0..1 (64 cols each)
    const int fr = l & 15;
    const int g  = l >> 4;

    const int split = blockIdx.x & 1;
    const int pxt   = blockIdx.x >> 1;   // 0..127
    const int px0 = pxt * BROW;
    const int kb0 = split * KSPLIT;

    // staging lane constants: pre-swizzled global source, linear LDS dest.
    const int srow = l >> 3;                  // 0..7
    const int ssw  = ((l & 7) ^ srow) * 8;
    const u16* asrc  = A  + (size_t)(px0 + w * 32 + srow) * 256 + ssw;
    const u16* bsrcw = eT + (size_t)(w * 16 + srow) * 256 + ssw;

    const f32x4 zacc = (f32x4){0.f, 0.f, 0.f, 0.f};
    f32x4 acc[4][4];
    int b1[16], b2[16];
#pragma unroll
    for (int i = 0; i < 16; ++i) { b1[i] = 0x7FFFFFFF; b2[i] = 0x7FFFFFFF; }

    // ---- prologue: B(nt0,kit0) + all of A (reused by all 32 nt); stays in flight, certified
    //      by the first kit's vmcnt(2) + barrier ----
    STAGE_B(kb0, 0, 0);
#pragma unroll
    for (int kit = 0; kit < 4; ++kit)
#pragma unroll
        for (int i = 0; i < 4; ++i)
            glds16(asrc + kit * 64 + (size_t)(i * 8) * 256,
                   &Ast[kit][(w * 32 + i * 8) * 64]);

    // ---- main loop: counted-vmcnt dual-barrier pipeline ----
    for (int nt = 0; nt < NTILES; ++nt) {
        const int n0 = kb0 + nt * BCOL;
#pragma unroll
        for (int kit = 0; kit < 4; ++kit) {
            const int cur = kit & 1;
            const bool has_next = (kit < 3) || (nt < NTILES - 1);
            if (kit < 3)        STAGE_B(n0, kit + 1, cur ^ 1);
            else if (has_next)  STAGE_B(n0 + BCOL, 0, cur ^ 1);
            if (has_next) { asm volatile("s_waitcnt vmcnt(2)" ::: "memory"); }
            else          { asm volatile("s_waitcnt vmcnt(0)" ::: "memory"); }
            __builtin_amdgcn_s_barrier();        // buf[cur] certified by every wave's vmcnt
            __builtin_amdgcn_sched_barrier(0);
            COMPUTE_KIT(kit, cur, kit == 0);
            __builtin_amdgcn_s_barrier();        // close WAR window on buf[cur] (no drain)
            __builtin_amdgcn_sched_barrier(0);
        }

        // epilogue: fold this nt's distances into per-row top-2 running keys (no LDS)
        float e2c[4];
        int   kc4[4];
#pragma unroll
        for (int ni = 0; ni < 4; ++ni) {
            kc4[ni] = n0 + wn * 64 + ni * 16 + fr;
            e2c[ni] = e2f[kc4[ni]] * 256.f;
        }
#pragma unroll
        for (int mi = 0; mi < 4; ++mi)
#pragma unroll
            for (int r = 0; r < 4; ++r) {
                int ky[4];
#pragma unroll
                for (int ni = 0; ni < 4; ++ni) {
                    float d = fmaf(acc[mi][ni][r], -512.f, e2c[ni]);
                    ky[ni] = (int)d * 8192 + kc4[ni];
                }
                int kmin = min(min(ky[0], ky[1]), min(ky[2], ky[3]));
                int s = mi * 4 + r;
                int v1 = min(b1[s], kmin);
                int x  = max(b1[s], kmin);
                b2[s] = min(b2[s], x);
                b1[s] = v1;
            }
    }

    // ---- per-wave 16-lane top-3 tree, then cross-wn merge via LDS (proven path) ----
    int* mrg = (int*)&Bd[0][0];   // 2*256*3 ints = 6 KB, Bd is dead now
#pragma unroll
    for (int s = 0; s < 16; ++s) {
        int c1 = b1[s], c2 = b2[s], c3 = 0x7FFFFFFF;
#pragma unroll
        for (int m = 1; m < 16; m <<= 1) {
            int a1 = __shfl_xor(c1, m, 64);
            int a2 = __shfl_xor(c2, m, 64);
            int a3 = __shfl_xor(c3, m, 64);
            int m1 = min(c1, a1);
            int xx = max(c1, a1);
            int mn2 = min(c2, a2);
            int m2 = min(xx, mn2);
            int m3 = min(min(max(c2, a2), max(xx, mn2)), min(c3, a3));
            c1 = m1; c2 = m2; c3 = m3;
        }
        if (fr == 0) {
            int row = wm * 64 + (s >> 2) * 16 + g * 4 + (s & 3);
            int o = (wn * 256 + row) * 3;
            mrg[o] = c1; mrg[o + 1] = c2; mrg[o + 2] = c3;
        }
    }
    __syncthreads();
    if (t < 256) {
        int a1 = mrg[t * 3], a2 = mrg[t * 3 + 1], a3 = mrg[t * 3 + 2];
        int u1 = mrg[(256 + t) * 3], u2 = mrg[(256 + t) * 3 + 1], u3 = mrg[(256 + t) * 3 + 2];
        int x1 = min(a1, u1), y1 = max(a1, u1);
        int n2 = min(a2, u2), M2 = max(a2, u2);
        int c1 = x1;
        int c2 = min(y1, n2);
        int c3 = min(max(y1, n2), min(M2, min(a3, u3)));
        int row = px0 + t;
        keys[split * NP + row]       = c1;
        keys[(2 + split) * NP + row] = c2;
        keys[(4 + split) * NP + row] = c3;
    }
}

// -------- finalize (fast-ws): dots + select + gather + out + loss, one pass (unchanged) --------
__global__ void finalize_kernel(const int* __restrict__ keys,
                                const float* __restrict__ z,
                                const float* __restrict__ eTf,
                                const float* __restrict__ e2f,
                                float* __restrict__ out,
                                float* __restrict__ loss) {
    __shared__ float smem[DD * 65];   // phase 1: zt[d*65+p]; phase 2: qt[p*257+d]
    __shared__ int   kc[384];
    __shared__ float dval[384];
    __shared__ int   kidx[64];
    const int t = threadIdx.x;
    const int n0 = blockIdx.x * 64;
    const float* zp = z + (size_t)(n0 >> 10) * (DD * HW) + (n0 & (HW - 1));

    for (int i = t; i < DD * 64; i += 256) {
        int d = i >> 6, p = i & 63;
        smem[d * 65 + p] = zp[(size_t)d * HW + p];   // coalesced
    }
    for (int i = t; i < 384; i += 256)
        kc[i] = keys[(i % 6) * NP + n0 + i / 6] & 8191;
    __syncthreads();

    const int l = t & 63, w = t >> 6;
    const int j = l & 15;   // lane within 16-lane dot group
    const int s = l >> 4;   // dot-group id within wave
#pragma unroll 2
    for (int it = 0; it < 24; ++it) {
        int dot = it * 16 + w * 4 + s;      // 0..383
        int p = dot / 6;
        int k = kc[dot];
        const float* er = eTf + (size_t)k * 256;
        float a = 0.f;
#pragma unroll
        for (int cc = 0; cc < 16; ++cc)
            a = fmaf(smem[(cc * 16 + j) * 65 + p], er[cc * 16 + j], a);
        a += __shfl_xor(a, 1, 64);
        a += __shfl_xor(a, 2, 64);
        a += __shfl_xor(a, 4, 64);
        a += __shfl_xor(a, 8, 64);
        if (j == 0) dval[dot] = fmaf(-2.f, a, e2f[k]);
    }
    __syncthreads();
    if (t < 64) {
        float bv = dval[t * 6];
        int   bk = kc[t * 6];
#pragma unroll
        for (int c = 1; c < 6; ++c) {
            float dv = dval[t * 6 + c];
            int   kk = kc[t * 6 + c];
            if (dv < bv || (dv == bv && kk < bk)) { bv = dv; bk = kk; }
        }
        kidx[t] = bk;
    }
    __syncthreads();

    // phase 2: bounce the 64 winning eTf rows through smem (zt is dead)
    float* qt = smem;                 // [p][d] pad 257 (257%32==1: conflict-free)
    for (int m = 0; m < 64; ++m)      // row m: 256 threads read the 1 KB row
        qt[m * 257 + t] = eTf[(size_t)kidx[m] * 256 + t];
    __syncthreads();

    const int p = t & 63, q = t >> 6;
    const size_t base = (size_t)(n0 >> 10) * (DD * HW) + (n0 & (HW - 1)) + p;
    float acc = 0.f;
#pragma unroll 8
    for (int i = 0; i < 64; ++i) {
        int d = q * 64 + i;
        float ev = qt[p * 257 + d];
        float zv = z[base + (size_t)d * HW];   // coalesced, L2-hot re-read
        out[base + (size_t)d * HW] = zv + (ev - zv);
        float df = ev - zv;
        acc = fmaf(df, df, acc);
    }
#pragma unroll
    for (int off = 32; off > 0; off >>= 1) acc += __shfl_down(acc, off, 64);
    __shared__ float part[4];
    if ((t & 63) == 0) part[t >> 6] = acc;
    __syncthreads();
    if (t == 0) {
        float s2 = (part[0] + part[1] + part[2] + part[3]) * (1.25f / 8388608.f);
        atomicAdd(loss, s2);
    }
}

// -------- slow-ws path: proven separate combine + gather (unchanged) --------
__global__ void combine_kernel(const int* __restrict__ keys,
                               const float* __restrict__ z,
                               const float* __restrict__ eTf,
                               const float* __restrict__ e2f,
                               int* __restrict__ idx) {
    __shared__ float zt[DD * 65];
    __shared__ int   kc[384];
    __shared__ float dval[384];
    const int t = threadIdx.x;
    const int n0 = blockIdx.x * 64;
    const float* zp = z + (size_t)(n0 >> 10) * (DD * HW) + (n0 & (HW - 1));
    for (int i = t; i < DD * 64; i += 256) {
        int d = i >> 6, p = i & 63;
        zt[d * 65 + p] = zp[(size_t)d * HW + p];
    }
    for (int i = t; i < 384; i += 256)
        kc[i] = keys[(i % 6) * NP + n0 + i / 6] & 8191;
    __syncthreads();

    const int l = t & 63, w = t >> 6;
    const int j = l & 15;
    const int s = l >> 4;
#pragma unroll 2
    for (int it = 0; it < 24; ++it) {
        int dot = it * 16 + w * 4 + s;
        int p = dot / 6;
        int k = kc[dot];
        const float* er = eTf + (size_t)k * 256;
        float a = 0.f;
#pragma unroll
        for (int cc = 0; cc < 16; ++cc)
            a = fmaf(zt[(cc * 16 + j) * 65 + p], er[cc * 16 + j], a);
        a += __shfl_xor(a, 1, 64);
        a += __shfl_xor(a, 2, 64);
        a += __shfl_xor(a, 4, 64);
        a += __shfl_xor(a, 8, 64);
        if (j == 0) dval[dot] = fmaf(-2.f, a, e2f[k]);
    }
    __syncthreads();
    if (t < 64) {
        float bv = dval[t * 6];
        int   bk = kc[t * 6];
#pragma unroll
        for (int c = 1; c < 6; ++c) {
            float dv = dval[t * 6 + c];
            int   kk = kc[t * 6 + c];
            if (dv < bv || (dv == bv && kk < bk)) { bv = dv; bk = kk; }
        }
        idx[n0 + t] = bk;
    }
}

__global__ void gather_slow_kernel(const float* __restrict__ z,
                                   const float* __restrict__ e,
                                   const int* __restrict__ idx,
                                   float* __restrict__ out,
                                   float* __restrict__ loss) {
    const int t = threadIdx.x;
    const int n0 = blockIdx.x * 64;
    __shared__ int kidx[64];
    if (t < 64) kidx[t] = idx[n0 + t];
    __syncthreads();

    const int p = t & 63;
    const int d0 = t >> 6;
    const size_t base = (size_t)(n0 >> 10) * (DD * HW) + (n0 & (HW - 1)) + p;
    const int kk = kidx[p];

    float acc = 0.f;
    for (int d = d0; d < DD; d += 4) {
        float ev = e[(size_t)d * KN + kk];
        float zv = z[base + (size_t)d * HW];
        out[base + (size_t)d * HW] = zv + (ev - zv);
        float df = ev - zv;
        acc = fmaf(df, df, acc);
    }
#pragma unroll
    for (int off = 32; off > 0; off >>= 1) acc += __shfl_down(acc, off, 64);
    __shared__ float part[4];
    if ((t & 63) == 0) part[t >> 6] = acc;
    __syncthreads();
    if (t == 0) {
        float s = (part[0] + part[1] + part[2] + part[3]) * (1.25f / 8388608.f);
        atomicAdd(loss, s);
    }
}

extern "C" void kernel_launch(void* const* d_in, const int* in_sizes, int n_in,
                              void* d_out, int out_size, void* d_ws, size_t ws_size,
                              hipStream_t stream) {
    const float* z = (const float*)d_in[0];   // [32,256,32,32] fp32
    const float* e = (const float*)d_in[1];   // [256,8192] fp32
    float* out = (float*)d_out;
    float* loss = out + (size_t)NP * DD;      // element 8388608

    char* ob = (char*)d_out;
    char* ws = (char*)d_ws;
    u16* Acat = (u16*)ob;                            // [0, 16Mi) — consumed by argmin
    u16* eT   = (u16*)(ob + ((size_t)16 << 20));     // [16Mi, 20Mi) — consumed by argmin

    float* e2f = (float*)ws;                         // 32 KB (proven-safe region)
    int*   idx = (int*)(ws + (32 << 10));            // 128 KB
    int*   keys;
    float* eTf;
    const bool fastws = ws_size >= ((size_t)10 << 20);
    if (fastws) {
        keys = (int*)(ws + (160 << 10));             // 768 KB @ 160K
        eTf  = (float*)(ws + ((size_t)1 << 20));     // 8 MB @ 1M
    } else {
        keys = (int*)(ob + ((size_t)20 << 20));      // d_out scratch (R6-proven)
        eTf  = (float*)(ob + ((size_t)23 << 20));
    }

    prep_kernel<<<2592, 256, 0, stream>>>(e, z, eT, eTf, e2f, Acat);
    argmin_mfma_kernel<<<SPLITS * (NP / BROW), 512, 0, stream>>>(Acat, eT, e2f, keys);
    hipMemsetAsync(loss, 0, sizeof(float), stream);
    if (fastws) {
        finalize_kernel<<<NP / 64, 256, 0, stream>>>(keys, z, eTf, e2f, out, loss);
    } else {
        combine_kernel<<<NP / 64, 256, 0, stream>>>(keys, z, eTf, e2f, idx);
        gather_slow_kernel<<<NP / 64, 256, 0, stream>>>(z, e, idx, out, loss);
    }
}

// Round 4
// 274.511 us; speedup vs baseline: 1.0855x; 1.0798x over previous
//
#include <hip/hip_runtime.h>

typedef unsigned int u32;
typedef unsigned short u16;
typedef __attribute__((ext_vector_type(8))) short bf16x8;  // 8 bf16 = 4 VGPRs
typedef __attribute__((ext_vector_type(4))) float f32x4;

#define KN 8192
#define DD 256
#define HW 1024
#define NP 32768
#define SPLITS 2
#define KSPLIT 4096
#define PXT 128
#define NTT 128

__device__ __forceinline__ u16 rne_bf16(float x) {
    u32 u = __float_as_uint(x);
    return (u16)((u + 0x7FFF + ((u >> 16) & 1)) >> 16);
}

__device__ __forceinline__ void glds16(const void* g, void* ldsbase) {
    __builtin_amdgcn_global_load_lds((const __attribute__((address_space(1))) u32*)g,
                                     (__attribute__((address_space(3))) u32*)ldsbase, 16, 0, 0);
}

// ---------------- merged prep: enorm | eT/eTf transpose | A build (unchanged, proven) ----------------
__global__ void prep_kernel(const float* __restrict__ e, const float* __restrict__ z,
                            u16* __restrict__ eT, float* __restrict__ eTf,
                            float* __restrict__ e2f, u16* __restrict__ A) {
    const int t = threadIdx.x;
    const int bid = blockIdx.x;
    if (bid < 32) {
        int k = bid * 256 + t;
        float acc = 0.f;
#pragma unroll 8
        for (int d = 0; d < DD; ++d) {
            float v = e[(size_t)d * KN + k];
            acc = fmaf(v, v, acc);
        }
        e2f[k] = acc;
    } else if (bid < 544) {
        __shared__ float tt[64][65];
        const int b2 = bid - 32;
        const int kt = b2 & 127;     // 0..127
        const int dt = b2 >> 7;      // 0..3
        const float* ep = e + (size_t)(dt * 64) * KN + kt * 64;
        {
            int k = t & 63, d0 = t >> 6;
#pragma unroll
            for (int j = 0; j < 16; ++j) tt[d0 + j * 4][k] = ep[(size_t)(d0 + j * 4) * KN + k];
        }
        __syncthreads();
        int k = t >> 2, c0 = (t & 3) * 16;
        u16 hi[16];
        float fv[16];
#pragma unroll
        for (int j = 0; j < 16; ++j) {
            float v = tt[c0 + j][k];
            fv[j] = v;
            hi[j] = rne_bf16(v);
        }
        u16* rowp = eT + (size_t)(kt * 64 + k) * 256 + dt * 64 + c0;
        *(uint4*)(rowp) = *(uint4*)(hi);
        *(uint4*)(rowp + 8) = *(uint4*)(hi + 8);
        float* rowpf = eTf + (size_t)(kt * 64 + k) * 256 + dt * 64 + c0;
#pragma unroll
        for (int j = 0; j < 4; ++j) *(float4*)(rowpf + j * 4) = *(float4*)(fv + j * 4);
    } else {
        __shared__ float tt[64][65];
        const int b3 = bid - 544;
        const int pt = b3 & 15;          // 0..15
        const int dt = (b3 >> 4) & 3;    // 0..3
        const int b  = b3 >> 6;          // 0..31
        const float* zp = z + (size_t)b * (DD * HW) + (size_t)(dt * 64) * HW + pt * 64;
        {
            int p = t & 63, d0 = t >> 6;
#pragma unroll
            for (int j = 0; j < 16; ++j) tt[d0 + j * 4][p] = zp[(size_t)(d0 + j * 4) * HW + p];
        }
        __syncthreads();
        int p = t >> 2, c0 = (t & 3) * 16;
        int n = b * HW + pt * 64 + p;
        u16 hi[16];
#pragma unroll
        for (int j = 0; j < 16; ++j) hi[j] = rne_bf16(tt[c0 + j][p]);
        u16* rowp = A + (size_t)n * 256 + dt * 64 + c0;
        *(uint4*)(rowp) = *(uint4*)(hi);
        *(uint4*)(rowp + 8) = *(uint4*)(hi + 8);
    }
}

// ---------------- main: R7-proven schedule, 64x64 wave tiles (R4) ----------------
// R4 post-mortem chain: R1 spill, R2 conflicts fixed but 1-block/CU lockstep slow, R3
// counted-vmcnt neutral -> the 8-wave/1-block structure itself was the regression.
// This round returns to R7's EXACT proven schedule (256 thr, 2 blocks/CU, 80 KB LDS,
// barrier/stage/barrier/compute per kit, 41% MfmaUtil @143.6us) and changes ONLY the
// wave-tile: 4 waves as 2x2 -> wave tile 64x64 (acc[4][4]), so per kc each wave does
// 4 af + 4 bfr ds_read_b128 for 16 MFMA = 512 B/MFMA vs R7's 640 (2+8 reads for 16).
// LDS-read is the measured binding pipe (R7: 5.24 GB total -> 76us floor vs 55us MFMA
// floor); cutting bytes 20% drops the floor to ~61us. Compute/epilogue/merge indexing
// is the R2/R3-proven code (absmax 0.0, 0 bank conflicts, 92 VGPR) at 128 rows.

__launch_bounds__(256, 2)
__global__ void argmin_mfma_kernel(const u16* __restrict__ A,   // [32768][256]
                                   const u16* __restrict__ eT,  // [8192][256]
                                   const float* __restrict__ e2f,
                                   int* __restrict__ keys) {    // [3][2][NP]
    __shared__ u16 Ast[4][PXT * 64];  // 64 KB resident A, XOR-swizzled slots
    __shared__ u16 Bst[NTT * 64];     // 16 KB streamed B

    const int t = threadIdx.x;
    const int w = t >> 6;        // wave 0..3
    const int l = t & 63;
    const int wm = w & 1;        // M-group: rows wm*64 .. +64
    const int wn = w >> 1;       // N-group: cols wn*64 .. +64
    const int split = blockIdx.x & 1;
    const int pxt   = blockIdx.x >> 1;
    const int px0 = pxt * PXT;
    const int kb0 = split * KSPLIT;

    const int swz  = (l & 7) ^ ((l >> 3) & 7);
    const int srow = l >> 3;
    const int fr = l & 15;
    const int g  = l >> 4;

    // ---- A prologue stage (identical to R7): rows w*32..+32, 4 kits ----
#pragma unroll
    for (int c = 0; c < 4; ++c)
#pragma unroll
        for (int i = 0; i < 4; ++i) {
            int r0 = w * 32 + i * 8;
            const u16* gp = A + (size_t)(px0 + r0 + srow) * 256 + c * 64 + swz * 8;
            glds16(gp, &Ast[c][r0 * 64]);
        }

    int b1[16], b2[16];
#pragma unroll
    for (int i = 0; i < 16; ++i) { b1[i] = 0x7FFFFFFF; b2[i] = 0x7FFFFFFF; }

    for (int nt = 0; nt < KSPLIT / NTT; ++nt) {
        const int n0 = kb0 + nt * NTT;
        f32x4 acc[4][4];
#pragma unroll
        for (int mi = 0; mi < 4; ++mi)
#pragma unroll
            for (int ni = 0; ni < 4; ++ni) acc[mi][ni] = (f32x4){0.f, 0.f, 0.f, 0.f};

        for (int kit = 0; kit < 4; ++kit) {
            __syncthreads();
#pragma unroll
            for (int i = 0; i < 4; ++i) {
                int r0 = w * 32 + i * 8;
                const u16* gp = eT + (size_t)(n0 + r0 + srow) * 256 + kit * 64 + swz * 8;
                glds16(gp, &Bst[r0 * 64]);
            }
            __syncthreads();
#pragma unroll
            for (int kc = 0; kc < 2; ++kc) {
                bf16x8 af[4], bfr[4];
#pragma unroll
                for (int mi = 0; mi < 4; ++mi) {
                    int row = wm * 64 + mi * 16 + fr;
                    int slt = (kc * 4 + g) ^ (row & 7);
                    af[mi] = *(const bf16x8*)&Ast[kit][row * 64 + slt * 8];
                }
#pragma unroll
                for (int ni = 0; ni < 4; ++ni) {
                    int row = wn * 64 + ni * 16 + fr;
                    int slt = (kc * 4 + g) ^ (row & 7);
                    bfr[ni] = *(const bf16x8*)&Bst[row * 64 + slt * 8];
                }
#pragma unroll
                for (int mi = 0; mi < 4; ++mi)
#pragma unroll
                    for (int ni = 0; ni < 4; ++ni)
                        acc[mi][ni] = __builtin_amdgcn_mfma_f32_16x16x32_bf16(
                            af[mi], bfr[ni], acc[mi][ni], 0, 0, 0);
            }
        }

        // fold this nt's distances into per-row running top-2 keys (R2/R3-proven indexing)
        float e2c[4];
        int   kc4[4];
#pragma unroll
        for (int ni = 0; ni < 4; ++ni) {
            kc4[ni] = n0 + wn * 64 + ni * 16 + fr;
            e2c[ni] = e2f[kc4[ni]] * 256.f;
        }
#pragma unroll
        for (int mi = 0; mi < 4; ++mi)
#pragma unroll
            for (int r = 0; r < 4; ++r) {
                int ky[4];
#pragma unroll
                for (int ni = 0; ni < 4; ++ni) {
                    float d = fmaf(acc[mi][ni][r], -512.f, e2c[ni]);
                    ky[ni] = (int)d * 8192 + kc4[ni];
                }
                int kmin = min(min(ky[0], ky[1]), min(ky[2], ky[3]));
                int s = mi * 4 + r;
                int v1 = min(b1[s], kmin);
                int x  = max(b1[s], kmin);
                b2[s] = min(b2[s], x);
                b1[s] = v1;
            }
    }

    // ---- per-wave 16-lane top-3 tree, then cross-wn merge via LDS (R2/R3-proven path) ----
    __syncthreads();               // all waves done reading Bst before overlay
    int* mrg = (int*)&Bst[0];      // 2*128*3 ints = 3 KB, Bst is dead now
#pragma unroll
    for (int s = 0; s < 16; ++s) {
        int c1 = b1[s], c2 = b2[s], c3 = 0x7FFFFFFF;
#pragma unroll
        for (int m = 1; m < 16; m <<= 1) {
            int a1 = __shfl_xor(c1, m, 64);
            int a2 = __shfl_xor(c2, m, 64);
            int a3 = __shfl_xor(c3, m, 64);
            int m1 = min(c1, a1);
            int xx = max(c1, a1);
            int mn2 = min(c2, a2);
            int m2 = min(xx, mn2);
            int m3 = min(min(max(c2, a2), max(xx, mn2)), min(c3, a3));
            c1 = m1; c2 = m2; c3 = m3;
        }
        if (fr == 0) {
            int row = wm * 64 + (s >> 2) * 16 + g * 4 + (s & 3);
            int o = (wn * 128 + row) * 3;
            mrg[o] = c1; mrg[o + 1] = c2; mrg[o + 2] = c3;
        }
    }
    __syncthreads();
    if (t < 128) {
        int a1 = mrg[t * 3], a2 = mrg[t * 3 + 1], a3 = mrg[t * 3 + 2];
        int u1 = mrg[(128 + t) * 3], u2 = mrg[(128 + t) * 3 + 1], u3 = mrg[(128 + t) * 3 + 2];
        int x1 = min(a1, u1), y1 = max(a1, u1);
        int n2 = min(a2, u2), M2 = max(a2, u2);
        int c1 = x1;
        int c2 = min(y1, n2);
        int c3 = min(max(y1, n2), min(M2, min(a3, u3)));
        int row = px0 + t;
        keys[split * NP + row]       = c1;
        keys[(2 + split) * NP + row] = c2;
        keys[(4 + split) * NP + row] = c3;
    }
}

// -------- finalize (fast-ws): dots + select + gather + out + loss, one pass (unchanged) --------
__global__ void finalize_kernel(const int* __restrict__ keys,
                                const float* __restrict__ z,
                                const float* __restrict__ eTf,
                                const float* __restrict__ e2f,
                                float* __restrict__ out,
                                float* __restrict__ loss) {
    __shared__ float smem[DD * 65];   // phase 1: zt[d*65+p]; phase 2: qt[p*257+d]
    __shared__ int   kc[384];
    __shared__ float dval[384];
    __shared__ int   kidx[64];
    const int t = threadIdx.x;
    const int n0 = blockIdx.x * 64;
    const float* zp = z + (size_t)(n0 >> 10) * (DD * HW) + (n0 & (HW - 1));

    for (int i = t; i < DD * 64; i += 256) {
        int d = i >> 6, p = i & 63;
        smem[d * 65 + p] = zp[(size_t)d * HW + p];   // coalesced
    }
    for (int i = t; i < 384; i += 256)
        kc[i] = keys[(i % 6) * NP + n0 + i / 6] & 8191;
    __syncthreads();

    const int l = t & 63, w = t >> 6;
    const int j = l & 15;   // lane within 16-lane dot group
    const int s = l >> 4;   // dot-group id within wave
#pragma unroll 2
    for (int it = 0; it < 24; ++it) {
        int dot = it * 16 + w * 4 + s;      // 0..383
        int p = dot / 6;
        int k = kc[dot];
        const float* er = eTf + (size_t)k * 256;
        float a = 0.f;
#pragma unroll
        for (int cc = 0; cc < 16; ++cc)
            a = fmaf(smem[(cc * 16 + j) * 65 + p], er[cc * 16 + j], a);
        a += __shfl_xor(a, 1, 64);
        a += __shfl_xor(a, 2, 64);
        a += __shfl_xor(a, 4, 64);
        a += __shfl_xor(a, 8, 64);
        if (j == 0) dval[dot] = fmaf(-2.f, a, e2f[k]);
    }
    __syncthreads();
    if (t < 64) {
        float bv = dval[t * 6];
        int   bk = kc[t * 6];
#pragma unroll
        for (int c = 1; c < 6; ++c) {
            float dv = dval[t * 6 + c];
            int   kk = kc[t * 6 + c];
            if (dv < bv || (dv == bv && kk < bk)) { bv = dv; bk = kk; }
        }
        kidx[t] = bk;
    }
    __syncthreads();

    // phase 2: bounce the 64 winning eTf rows through smem (zt is dead)
    float* qt = smem;                 // [p][d] pad 257 (257%32==1: conflict-free)
    for (int m = 0; m < 64; ++m)      // row m: 256 threads read the 1 KB row
        qt[m * 257 + t] = eTf[(size_t)kidx[m] * 256 + t];
    __syncthreads();

    const int p = t & 63, q = t >> 6;
    const size_t base = (size_t)(n0 >> 10) * (DD * HW) + (n0 & (HW - 1)) + p;
    float acc = 0.f;
#pragma unroll 8
    for (int i = 0; i < 64; ++i) {
        int d = q * 64 + i;
        float ev = qt[p * 257 + d];
        float zv = z[base + (size_t)d * HW];   // coalesced, L2-hot re-read
        out[base + (size_t)d * HW] = zv + (ev - zv);
        float df = ev - zv;
        acc = fmaf(df, df, acc);
    }
#pragma unroll
    for (int off = 32; off > 0; off >>= 1) acc += __shfl_down(acc, off, 64);
    __shared__ float part[4];
    if ((t & 63) == 0) part[t >> 6] = acc;
    __syncthreads();
    if (t == 0) {
        float s2 = (part[0] + part[1] + part[2] + part[3]) * (1.25f / 8388608.f);
        atomicAdd(loss, s2);
    }
}

// -------- slow-ws path: proven separate combine + gather (unchanged) --------
__global__ void combine_kernel(const int* __restrict__ keys,
                               const float* __restrict__ z,
                               const float* __restrict__ eTf,
                               const float* __restrict__ e2f,
                               int* __restrict__ idx) {
    __shared__ float zt[DD * 65];
    __shared__ int   kc[384];
    __shared__ float dval[384];
    const int t = threadIdx.x;
    const int n0 = blockIdx.x * 64;
    const float* zp = z + (size_t)(n0 >> 10) * (DD * HW) + (n0 & (HW - 1));
    for (int i = t; i < DD * 64; i += 256) {
        int d = i >> 6, p = i & 63;
        zt[d * 65 + p] = zp[(size_t)d * HW + p];
    }
    for (int i = t; i < 384; i += 256)
        kc[i] = keys[(i % 6) * NP + n0 + i / 6] & 8191;
    __syncthreads();

    const int l = t & 63, w = t >> 6;
    const int j = l & 15;
    const int s = l >> 4;
#pragma unroll 2
    for (int it = 0; it < 24; ++it) {
        int dot = it * 16 + w * 4 + s;
        int p = dot / 6;
        int k = kc[dot];
        const float* er = eTf + (size_t)k * 256;
        float a = 0.f;
#pragma unroll
        for (int cc = 0; cc < 16; ++cc)
            a = fmaf(zt[(cc * 16 + j) * 65 + p], er[cc * 16 + j], a);
        a += __shfl_xor(a, 1, 64);
        a += __shfl_xor(a, 2, 64);
        a += __shfl_xor(a, 4, 64);
        a += __shfl_xor(a, 8, 64);
        if (j == 0) dval[dot] = fmaf(-2.f, a, e2f[k]);
    }
    __syncthreads();
    if (t < 64) {
        float bv = dval[t * 6];
        int   bk = kc[t * 6];
#pragma unroll
        for (int c = 1; c < 6; ++c) {
            float dv = dval[t * 6 + c];
            int   kk = kc[t * 6 + c];
            if (dv < bv || (dv == bv && kk < bk)) { bv = dv; bk = kk; }
        }
        idx[n0 + t] = bk;
    }
}

__global__ void gather_slow_kernel(const float* __restrict__ z,
                                   const float* __restrict__ e,
                                   const int* __restrict__ idx,
                                   float* __restrict__ out,
                                   float* __restrict__ loss) {
    const int t = threadIdx.x;
    const int n0 = blockIdx.x * 64;
    __shared__ int kidx[64];
    if (t < 64) kidx[t] = idx[n0 + t];
    __syncthreads();

    const int p = t & 63;
    const int d0 = t >> 6;
    const size_t base = (size_t)(n0 >> 10) * (DD * HW) + (n0 & (HW - 1)) + p;
    const int kk = kidx[p];

    float acc = 0.f;
    for (int d = d0; d < DD; d += 4) {
        float ev = e[(size_t)d * KN + kk];
        float zv = z[base + (size_t)d * HW];
        out[base + (size_t)d * HW] = zv + (ev - zv);
        float df = ev - zv;
        acc = fmaf(df, df, acc);
    }
#pragma unroll
    for (int off = 32; off > 0; off >>= 1) acc += __shfl_down(acc, off, 64);
    __shared__ float part[4];
    if ((t & 63) == 0) part[t >> 6] = acc;
    __syncthreads();
    if (t == 0) {
        float s = (part[0] + part[1] + part[2] + part[3]) * (1.25f / 8388608.f);
        atomicAdd(loss, s);
    }
}

extern "C" void kernel_launch(void* const* d_in, const int* in_sizes, int n_in,
                              void* d_out, int out_size, void* d_ws, size_t ws_size,
                              hipStream_t stream) {
    const float* z = (const float*)d_in[0];   // [32,256,32,32] fp32
    const float* e = (const float*)d_in[1];   // [256,8192] fp32
    float* out = (float*)d_out;
    float* loss = out + (size_t)NP * DD;      // element 8388608

    char* ob = (char*)d_out;
    char* ws = (char*)d_ws;
    u16* Acat = (u16*)ob;                            // [0, 16Mi) — consumed by argmin
    u16* eT   = (u16*)(ob + ((size_t)16 << 20));     // [16Mi, 20Mi) — consumed by argmin

    float* e2f = (float*)ws;                         // 32 KB (proven-safe region)
    int*   idx = (int*)(ws + (32 << 10));            // 128 KB
    int*   keys;
    float* eTf;
    const bool fastws = ws_size >= ((size_t)10 << 20);
    if (fastws) {
        keys = (int*)(ws + (160 << 10));             // 768 KB @ 160K
        eTf  = (float*)(ws + ((size_t)1 << 20));     // 8 MB @ 1M
    } else {
        keys = (int*)(ob + ((size_t)20 << 20));      // d_out scratch (R6-proven)
        eTf  = (float*)(ob + ((size_t)23 << 20));
    }

    prep_kernel<<<2592, 256, 0, stream>>>(e, z, eT, eTf, e2f, Acat);
    argmin_mfma_kernel<<<SPLITS * (NP / PXT), 256, 0, stream>>>(Acat, eT, e2f, keys);
    hipMemsetAsync(loss, 0, sizeof(float), stream);
    if (fastws) {
        finalize_kernel<<<NP / 64, 256, 0, stream>>>(keys, z, eTf, e2f, out, loss);
    } else {
        combine_kernel<<<NP / 64, 256, 0, stream>>>(keys, z, eTf, e2f, idx);
        gather_slow_kernel<<<NP / 64, 256, 0, stream>>>(z, e, idx, out, loss);
    }
}